// Round 1
// baseline (166.728 us; speedup 1.0000x reference)
//
#include <hip/hip_runtime.h>

#define EPS_F 1e-6f

// ---- Kernel 1: w = sigmoid(w_raw), 19x19 = 361 floats into d_ws ----
__global__ void sigmoid_w_kernel(const float* __restrict__ w_raw,
                                 float* __restrict__ w) {
    int i = threadIdx.x;
    if (i < 361) {
        w[i] = 1.0f / (1.0f + expf(-w_raw[i]));
    }
}

__device__ __forceinline__ float mixf(float a, float b, float wv) {
    float mn = fminf(a, b);
    float mx = fmaxf(a, b);
    // w*mn + (1-w)*mx == mx + w*(mn-mx)
    return fmaf(wv, mn - mx, mx);
}

// ---- Kernel 2: one thread per sample, 19 trees, 19 nodes/tree ----
__global__ __launch_bounds__(256) void tree_forward_kernel(
    const float* __restrict__ c20,   // (B, 20)
    const float* __restrict__ w,     // (19, 19) sigmoid'd, row t = tree t
    float* __restrict__ out,         // (B, 19)
    int B)
{
    int s = blockIdx.x * blockDim.x + threadIdx.x;
    if (s >= B) return;

    // Load the 20-float row as 5 aligned float4 (row stride 80 B, 16B aligned).
    float x[20];
    const float4* src = reinterpret_cast<const float4*>(c20 + (size_t)s * 20);
    #pragma unroll
    for (int q = 0; q < 5; ++q) {
        float4 v = src[q];
        x[4*q + 0] = v.x;
        x[4*q + 1] = v.y;
        x[4*q + 2] = v.z;
        x[4*q + 3] = v.w;
    }

    float* dst = out + (size_t)s * 19;

    // Fully unrolled: all weight indices are compile-time constants off the
    // uniform pointer `w` -> scalar (SMEM) loads, broadcast to the wave.
    #pragma unroll
    for (int t = 0; t < 19; ++t) {
        const float* wr = w + t * 19;

        // layer 0: width 20 -> 10 nodes, weights wr[0..9]
        float y[10];
        #pragma unroll
        for (int k = 0; k < 10; ++k)
            y[k] = mixf(x[2*k], x[2*k + 1], wr[k]);

        // layer 1: width 10 -> 5 nodes, weights wr[10..14]
        float z[5];
        #pragma unroll
        for (int k = 0; k < 5; ++k)
            z[k] = mixf(y[2*k], y[2*k + 1], wr[10 + k]);

        // layer 2: width 5 -> 2 nodes + carry z[4], weights wr[15..16]
        float u0 = mixf(z[0], z[1], wr[15]);
        float u1 = mixf(z[2], z[3], wr[16]);
        float u2 = z[4];

        // layer 3: width 3 -> 1 node + carry u2, weight wr[17]
        float v0 = mixf(u0, u1, wr[17]);

        // layer 4: width 2 -> 1 node, weight wr[18]
        float r = mixf(v0, u2, wr[18]);

        dst[t] = fminf(fmaxf(r, EPS_F), 1.0f - EPS_F);
    }
}

extern "C" void kernel_launch(void* const* d_in, const int* in_sizes, int n_in,
                              void* d_out, int out_size, void* d_ws, size_t ws_size,
                              hipStream_t stream) {
    // setup_inputs order: p1 (B,) int, p2 (B,) int, c20 (B,20) f32, w_raw (19,19) f32
    const float* c20   = (const float*)d_in[2];
    const float* w_raw = (const float*)d_in[3];
    float* out = (float*)d_out;
    float* w   = (float*)d_ws;   // 361 floats of scratch

    int B = in_sizes[0];

    sigmoid_w_kernel<<<1, 384, 0, stream>>>(w_raw, w);

    int block = 256;
    int grid = (B + block - 1) / block;
    tree_forward_kernel<<<grid, block, 0, stream>>>(c20, w, out, B);
}

// Round 2
// 158.401 us; speedup vs baseline: 1.0526x; 1.0526x over previous
//
#include <hip/hip_runtime.h>

#define EPS_F 1e-6f
#define BLK   256
#define SPB   512   // samples per block (2 per thread)

// ---- Kernel 1: w = sigmoid(w_raw), 19x19 = 361 floats into d_ws ----
__global__ void sigmoid_w_kernel(const float* __restrict__ w_raw,
                                 float* __restrict__ w) {
    int i = threadIdx.x;
    if (i < 361) {
        w[i] = 1.0f / (1.0f + expf(-w_raw[i]));
    }
}

__device__ __forceinline__ float mixf(float a, float b, float wv) {
    float mn = fminf(a, b);
    float mx = fmaxf(a, b);
    // w*mn + (1-w)*mx == mx + w*(mn-mx)
    return fmaf(wv, mn - mx, mx);
}

// ---- Kernel 2: 2 samples/thread, LDS-staged coalesced output ----
__global__ __launch_bounds__(BLK) void tree_forward_kernel(
    const float* __restrict__ c20,   // (B, 20)
    const float* __restrict__ w,     // (19, 19) sigmoid'd
    float* __restrict__ out,         // (B, 19)
    int B)
{
    __shared__ float so[SPB * 19];   // 38912 B

    const int tid = threadIdx.x;
    const long long S0 = (long long)blockIdx.x * SPB;
    const long long sA = S0 + tid;          // sample A
    const long long sB = S0 + BLK + tid;    // sample B

    float xa[20], xb[20];

    if (sA < B) {
        const float4* p = reinterpret_cast<const float4*>(c20 + sA * 20);
        #pragma unroll
        for (int q = 0; q < 5; ++q) {
            float4 v = p[q];
            xa[4*q+0] = v.x; xa[4*q+1] = v.y; xa[4*q+2] = v.z; xa[4*q+3] = v.w;
        }
    } else {
        #pragma unroll
        for (int i = 0; i < 20; ++i) xa[i] = 0.0f;
    }
    if (sB < B) {
        const float4* p = reinterpret_cast<const float4*>(c20 + sB * 20);
        #pragma unroll
        for (int q = 0; q < 5; ++q) {
            float4 v = p[q];
            xb[4*q+0] = v.x; xb[4*q+1] = v.y; xb[4*q+2] = v.z; xb[4*q+3] = v.w;
        }
    } else {
        #pragma unroll
        for (int i = 0; i < 20; ++i) xb[i] = 0.0f;
    }

    float* __restrict__ oA = &so[tid * 19];
    float* __restrict__ oB = &so[(tid + BLK) * 19];

    #pragma unroll
    for (int t = 0; t < 19; ++t) {
        const float* wr = w + t * 19;

        // layer 0: 20 -> 10, weights wr[0..9]
        float ya[10], yb[10];
        #pragma unroll
        for (int k = 0; k < 10; ++k) {
            float wv = wr[k];
            ya[k] = mixf(xa[2*k], xa[2*k+1], wv);
            yb[k] = mixf(xb[2*k], xb[2*k+1], wv);
        }

        // layer 1: 10 -> 5, weights wr[10..14]
        float za[5], zb[5];
        #pragma unroll
        for (int k = 0; k < 5; ++k) {
            float wv = wr[10 + k];
            za[k] = mixf(ya[2*k], ya[2*k+1], wv);
            zb[k] = mixf(yb[2*k], yb[2*k+1], wv);
        }

        // layer 2: 5 -> 2 + carry, weights wr[15..16]
        float w15 = wr[15], w16 = wr[16];
        float ua0 = mixf(za[0], za[1], w15);
        float ub0 = mixf(zb[0], zb[1], w15);
        float ua1 = mixf(za[2], za[3], w16);
        float ub1 = mixf(zb[2], zb[3], w16);
        float ua2 = za[4];
        float ub2 = zb[4];

        // layer 3: 3 -> 1 + carry, weight wr[17]
        float w17 = wr[17];
        float va = mixf(ua0, ua1, w17);
        float vb = mixf(ub0, ub1, w17);

        // layer 4: 2 -> 1, weight wr[18]
        float w18 = wr[18];
        float ra = mixf(va, ua2, w18);
        float rb = mixf(vb, ub2, w18);

        oA[t] = fminf(fmaxf(ra, EPS_F), 1.0f - EPS_F);
        oB[t] = fminf(fmaxf(rb, EPS_F), 1.0f - EPS_F);
    }

    __syncthreads();

    // Cooperative coalesced copy-out: SPB*19 = 9728 dwords = 2432 float4.
    const long long nDw    = (long long)B * 19;
    const long long baseDw = S0 * 19;            // divisible by 4 (9728 per block)
    const float4* ls = reinterpret_cast<const float4*>(so);

    for (int i = tid; i < (SPB * 19) / 4; i += BLK) {
        long long g = baseDw + (long long)i * 4;
        if (g + 3 < nDw) {
            *reinterpret_cast<float4*>(out + g) = ls[i];
        } else if (g < nDw) {
            float4 v = ls[i];
            out[g] = v.x;
            if (g + 1 < nDw) out[g + 1] = v.y;
            if (g + 2 < nDw) out[g + 2] = v.z;
        }
    }
}

extern "C" void kernel_launch(void* const* d_in, const int* in_sizes, int n_in,
                              void* d_out, int out_size, void* d_ws, size_t ws_size,
                              hipStream_t stream) {
    // setup_inputs order: p1 (B,) int, p2 (B,) int, c20 (B,20) f32, w_raw (19,19) f32
    const float* c20   = (const float*)d_in[2];
    const float* w_raw = (const float*)d_in[3];
    float* out = (float*)d_out;
    float* w   = (float*)d_ws;   // 361 floats of scratch

    int B = in_sizes[0];

    sigmoid_w_kernel<<<1, 384, 0, stream>>>(w_raw, w);

    int grid = (B + SPB - 1) / SPB;
    tree_forward_kernel<<<grid, BLK, 0, stream>>>(c20, w, out, B);
}

// Round 3
// 155.682 us; speedup vs baseline: 1.0709x; 1.0175x over previous
//
#include <hip/hip_runtime.h>

#define EPS_F 1e-6f
#define BLK   256
#define SPB   256   // samples per block = 1 per thread (LDS 19456 B -> 8 blocks/CU)

// ---- Kernel 1: w = sigmoid(w_raw), 19x19 = 361 floats into d_ws ----
__global__ void sigmoid_w_kernel(const float* __restrict__ w_raw,
                                 float* __restrict__ w) {
    int i = threadIdx.x;
    if (i < 361) {
        w[i] = 1.0f / (1.0f + expf(-w_raw[i]));
    }
}

__device__ __forceinline__ float mixf(float a, float b, float wv) {
    float mn = fminf(a, b);
    float mx = fmaxf(a, b);
    // w*mn + (1-w)*mx == mx + w*(mn-mx)
    return fmaf(wv, mn - mx, mx);
}

// ---- Kernel 2: 1 sample/thread, LDS-staged coalesced output ----
__global__ __launch_bounds__(BLK) void tree_forward_kernel(
    const float* __restrict__ c20,   // (B, 20)
    const float* __restrict__ w,     // (19, 19) sigmoid'd
    float* __restrict__ out,         // (B, 19)
    int B)
{
    __shared__ float so[SPB * 19];   // 19456 B -> 8 blocks/CU -> 32 waves/CU

    const int tid = threadIdx.x;
    const long long S0 = (long long)blockIdx.x * SPB;
    const long long s  = S0 + tid;

    float x[20];
    if (s < B) {
        const float4* p = reinterpret_cast<const float4*>(c20 + s * 20);
        #pragma unroll
        for (int q = 0; q < 5; ++q) {
            float4 v = p[q];
            x[4*q+0] = v.x; x[4*q+1] = v.y; x[4*q+2] = v.z; x[4*q+3] = v.w;
        }
    } else {
        #pragma unroll
        for (int i = 0; i < 20; ++i) x[i] = 0.0f;
    }

    float* __restrict__ o = &so[tid * 19];

    #pragma unroll
    for (int t = 0; t < 19; ++t) {
        const float* wr = w + t * 19;

        // layer 0: 20 -> 10, weights wr[0..9]
        float y[10];
        #pragma unroll
        for (int k = 0; k < 10; ++k)
            y[k] = mixf(x[2*k], x[2*k+1], wr[k]);

        // layer 1: 10 -> 5, weights wr[10..14]
        float z[5];
        #pragma unroll
        for (int k = 0; k < 5; ++k)
            z[k] = mixf(y[2*k], y[2*k+1], wr[10 + k]);

        // layer 2: 5 -> 2 + carry, weights wr[15..16]
        float u0 = mixf(z[0], z[1], wr[15]);
        float u1 = mixf(z[2], z[3], wr[16]);
        float u2 = z[4];

        // layer 3: 3 -> 1 + carry, weight wr[17]
        float v0 = mixf(u0, u1, wr[17]);

        // layer 4: 2 -> 1, weight wr[18]
        float r = mixf(v0, u2, wr[18]);

        o[t] = fminf(fmaxf(r, EPS_F), 1.0f - EPS_F);
    }

    __syncthreads();

    // Cooperative coalesced copy-out: SPB*19 = 4864 dwords = 1216 float4.
    const long long nDw    = (long long)B * 19;
    const long long baseDw = S0 * 19;            // 4864/block -> divisible by 4
    const float4* ls = reinterpret_cast<const float4*>(so);

    #pragma unroll
    for (int i = tid; i < (SPB * 19) / 4; i += BLK) {
        long long g = baseDw + (long long)i * 4;
        if (g + 3 < nDw) {
            *reinterpret_cast<float4*>(out + g) = ls[i];
        } else if (g < nDw) {
            float4 v = ls[i];
            out[g] = v.x;
            if (g + 1 < nDw) out[g + 1] = v.y;
            if (g + 2 < nDw) out[g + 2] = v.z;
        }
    }
}

extern "C" void kernel_launch(void* const* d_in, const int* in_sizes, int n_in,
                              void* d_out, int out_size, void* d_ws, size_t ws_size,
                              hipStream_t stream) {
    // setup_inputs order: p1 (B,) int, p2 (B,) int, c20 (B,20) f32, w_raw (19,19) f32
    const float* c20   = (const float*)d_in[2];
    const float* w_raw = (const float*)d_in[3];
    float* out = (float*)d_out;
    float* w   = (float*)d_ws;   // 361 floats of scratch

    int B = in_sizes[0];

    sigmoid_w_kernel<<<1, 384, 0, stream>>>(w_raw, w);

    int grid = (B + SPB - 1) / SPB;
    tree_forward_kernel<<<grid, BLK, 0, stream>>>(c20, w, out, B);
}